// Round 2
// baseline (7355.157 us; speedup 1.0000x reference)
//
#include <hip/hip_runtime.h>
#include <cmath>

#define N_NODES 50000
#define N_EDGES 800000
#define D_IN    128
#define D_HID   256
#define D_OUT   47
#define BN_EPS  1e-5f

// ---------------------------------------------------------------------------
// edge_index layout detection: reference declares int64. If the harness keeps
// int64 (little-endian, values < 50000), every odd 32-bit word is 0. If it
// converts to int32, odd words are random node ids.  flag=1 -> int64 layout.
// ---------------------------------------------------------------------------
__global__ void detect_idx_kernel(const int* __restrict__ ei, int* __restrict__ flag) {
    __shared__ int any_nonzero;
    if (threadIdx.x == 0) any_nonzero = 0;
    __syncthreads();
    int v = ei[2 * threadIdx.x + 1];
    if (v != 0) atomicAdd(&any_nonzero, 1);
    __syncthreads();
    if (threadIdx.x == 0) *flag = (any_nonzero == 0) ? 1 : 0;
}

__device__ __forceinline__ int load_edge(const int* __restrict__ ei, int e, int which, int is64) {
    if (is64) return ei[2 * ((long long)which * N_EDGES + e)];
    return ei[(long long)which * N_EDGES + e];
}

// ---------------------------------------------------------------------------
// degree + inverse degree
// ---------------------------------------------------------------------------
__global__ void deg_kernel(const int* __restrict__ ei, const int* __restrict__ flag,
                           float* __restrict__ deg) {
    int e = blockIdx.x * blockDim.x + threadIdx.x;
    if (e >= N_EDGES) return;
    int is64 = *flag;
    int d = load_edge(ei, e, 1, is64);
    atomicAdd(&deg[d], 1.0f);
}

__global__ void inv_deg_kernel(float* __restrict__ deg) {
    int i = blockIdx.x * blockDim.x + threadIdx.x;
    if (i < N_NODES) deg[i] = 1.0f / fmaxf(deg[i], 1.0f);
}

// ---------------------------------------------------------------------------
// chunked scatter-add: agg[dst[e], 0:CC] += x[src[e], c0:c0+CC]
// agg row stride = CC. chsh = log2(CC/4).
// ---------------------------------------------------------------------------
__global__ void scatter_chunk(const float* __restrict__ x, int ldx, int c0, int CC, int chsh,
                              const int* __restrict__ ei, const int* __restrict__ flag,
                              float* __restrict__ agg) {
    const int idx = blockIdx.x * blockDim.x + threadIdx.x;
    const int e = idx >> chsh;
    if (e >= N_EDGES) return;
    const int c = (idx & ((1 << chsh) - 1)) * 4;
    const int is64 = *flag;
    const int s = load_edge(ei, e, 0, is64);
    const int d = load_edge(ei, e, 1, is64);
    const float4 v = *(const float4*)(x + (long long)s * ldx + c0 + c);
    float* p = agg + (long long)d * CC + c;
    atomicAdd(p + 0, v.x);
    atomicAdd(p + 1, v.y);
    atomicAdd(p + 2, v.z);
    atomicAdd(p + 3, v.w);
}

// ---------------------------------------------------------------------------
// Fused SAGE layer GEMM (chunk-accumulating):
//   partial = (Aagg * inv_deg[row]) @ Wl_sub           (K = K_agg = chunk cols)
//   C = (first ? 0 : C) + partial
//       + (last ? X @ Wr + bias [+ BN + ReLU] : 0)
// 64x64 tile, 256 threads, 4x4 micro-tile per thread, BK=16.
// Requires K_agg and K_x multiples of 16.
// ---------------------------------------------------------------------------
#define BM 64
#define BN 64
#define BK 16

__global__ __launch_bounds__(256) void sage_gemm(
    const float* __restrict__ Aagg, const float* __restrict__ invdeg,
    const float* __restrict__ X,
    const float* __restrict__ Wl_sub, const float* __restrict__ Wr,
    const float* __restrict__ bias,
    const float* __restrict__ gamma, const float* __restrict__ beta,
    const float* __restrict__ mean, const float* __restrict__ var,
    float* __restrict__ C, int K_agg, int K_x, int M,
    int first, int last, int bn_relu)
{
    __shared__ float As[BK][BM + 4];
    __shared__ float Bs[BK][BN + 4];

    const int tid = threadIdx.x;
    const int tx = tid & 15;
    const int ty = tid >> 4;
    const int row0 = blockIdx.y * BM;
    const int col0 = blockIdx.x * BN;

    float acc[4][4];
#pragma unroll
    for (int i = 0; i < 4; ++i)
#pragma unroll
        for (int j = 0; j < 4; ++j) acc[i][j] = 0.0f;

    const int ar = tid >> 2;        // tile row 0..63
    const int ak = (tid & 3) * 4;   // k offset 0,4,8,12
    const int bc = tid & 63;        // tile col
    const int bk = tid >> 6;        // 0..3

    for (int pass = 0; pass < 2; ++pass) {
        if (pass == 1 && !last) break;
        const float* __restrict__ A = pass ? X : Aagg;
        const float* __restrict__ B = pass ? Wr : Wl_sub;
        const int K = pass ? K_x : K_agg;

        for (int k0 = 0; k0 < K; k0 += BK) {
            const int grow = row0 + ar;
            float4 av = make_float4(0.f, 0.f, 0.f, 0.f);
            float scale = 1.0f;
            if (grow < N_NODES) {
                av = *(const float4*)(A + (long long)grow * K + k0 + ak);
                if (pass == 0) scale = invdeg[grow];
            }
            As[ak + 0][ar] = av.x * scale;
            As[ak + 1][ar] = av.y * scale;
            As[ak + 2][ar] = av.z * scale;
            As[ak + 3][ar] = av.w * scale;

            const int gcol = col0 + bc;
#pragma unroll
            for (int j = 0; j < 4; ++j) {
                const int krow = k0 + bk + j * 4;
                Bs[bk + j * 4][bc] = (gcol < M) ? B[(long long)krow * M + gcol] : 0.0f;
            }
            __syncthreads();

#pragma unroll
            for (int kk = 0; kk < BK; ++kk) {
                float a[4], b[4];
#pragma unroll
                for (int i = 0; i < 4; ++i) a[i] = As[kk][ty * 4 + i];
#pragma unroll
                for (int j = 0; j < 4; ++j) b[j] = Bs[kk][tx * 4 + j];
#pragma unroll
                for (int i = 0; i < 4; ++i)
#pragma unroll
                    for (int j = 0; j < 4; ++j) acc[i][j] += a[i] * b[j];
            }
            __syncthreads();
        }
    }

    // ---- epilogue ----
#pragma unroll
    for (int i = 0; i < 4; ++i) {
        const int row = row0 + ty * 4 + i;
        if (row >= N_NODES) continue;
#pragma unroll
        for (int j = 0; j < 4; ++j) {
            const int col = col0 + tx * 4 + j;
            if (col >= M) continue;
            const long long off = (long long)row * M + col;
            float v = acc[i][j];
            if (!first) v += C[off];
            if (last) {
                v += bias[col];
                if (bn_relu) {
                    v = (v - mean[col]) * (gamma[col] * rsqrtf(var[col] + BN_EPS)) + beta[col];
                    v = fmaxf(v, 0.0f);
                }
            }
            C[off] = v;
        }
    }
}

// ---------------------------------------------------------------------------
// log_softmax over rows of 47 — one wave (64 lanes) per row
// ---------------------------------------------------------------------------
__global__ void log_softmax_kernel(const float* __restrict__ z, float* __restrict__ y) {
    const int gtid = blockIdx.x * blockDim.x + threadIdx.x;
    const int row = gtid >> 6;
    const int lane = threadIdx.x & 63;
    if (row >= N_NODES) return;

    const float* zr = z + (long long)row * D_OUT;
    float v = (lane < D_OUT) ? zr[lane] : -INFINITY;

    float m = v;
#pragma unroll
    for (int off = 32; off > 0; off >>= 1) m = fmaxf(m, __shfl_down(m, off));
    m = __shfl(m, 0);

    float ev = (lane < D_OUT) ? expf(v - m) : 0.0f;
    float s = ev;
#pragma unroll
    for (int off = 32; off > 0; off >>= 1) s += __shfl_down(s, off);
    s = __shfl(s, 0);

    if (lane < D_OUT) y[(long long)row * D_OUT + lane] = v - m - logf(s);
}

// ---------------------------------------------------------------------------
// host-side: one SAGE layer via column-chunked aggregation
// ---------------------------------------------------------------------------
static void run_layer(const float* Xin, int K, const float* Wl, const float* Wr,
                      const float* bias, const float* g, const float* b,
                      const float* m, const float* v, float* Cout, int M, int bn_relu,
                      int chunk, float* agg, float* invdeg,
                      const int* ei, const int* flag, hipStream_t stream)
{
    const int CC = (chunk < K) ? chunk : K;
    const int nchunks = K / CC;
    const int chsh = __builtin_ctz(CC / 4);
    const long long sc_threads = (long long)N_EDGES << chsh;
    const dim3 gGemm((M + BN - 1) / BN, (N_NODES + BM - 1) / BM);

    for (int c = 0; c < nchunks; ++c) {
        const int c0 = c * CC;
        hipMemsetAsync(agg, 0, (size_t)N_NODES * CC * sizeof(float), stream);
        scatter_chunk<<<(sc_threads + 255) / 256, 256, 0, stream>>>(
            Xin, K, c0, CC, chsh, ei, flag, agg);
        sage_gemm<<<gGemm, 256, 0, stream>>>(
            agg, invdeg, Xin, Wl + (long long)c0 * M, Wr, bias,
            g, b, m, v, Cout, CC, K, M,
            (c == 0) ? 1 : 0, (c == nchunks - 1) ? 1 : 0, bn_relu);
    }
}

// ---------------------------------------------------------------------------
// launch
// ---------------------------------------------------------------------------
extern "C" void kernel_launch(void* const* d_in, const int* in_sizes, int n_in,
                              void* d_out, int out_size, void* d_ws, size_t ws_size,
                              hipStream_t stream) {
    const float* x     = (const float*)d_in[0];
    const int*   ei    = (const int*)d_in[1];
    const float* W1_l  = (const float*)d_in[2];
    const float* b1    = (const float*)d_in[3];
    const float* W1_r  = (const float*)d_in[4];
    const float* bn1_g = (const float*)d_in[5];
    const float* bn1_b = (const float*)d_in[6];
    const float* bn1_m = (const float*)d_in[7];
    const float* bn1_v = (const float*)d_in[8];
    const float* W2_l  = (const float*)d_in[9];
    const float* b2    = (const float*)d_in[10];
    const float* W2_r  = (const float*)d_in[11];
    const float* bn2_g = (const float*)d_in[12];
    const float* bn2_b = (const float*)d_in[13];
    const float* bn2_m = (const float*)d_in[14];
    const float* bn2_v = (const float*)d_in[15];
    const float* W3_l  = (const float*)d_in[16];
    const float* b3    = (const float*)d_in[17];
    const float* W3_r  = (const float*)d_in[18];

    // --- workspace layout (STRICTLY within ws_size) ---
    char* ws = (char*)d_ws;
    float* deg  = (float*)ws;                 // N floats = 200,000 B
    int*   flag = (int*)(ws + 200704);        // 1 int
    float* agg  = (float*)(ws + 201216);      // remaining bytes
    const size_t avail = (ws_size > 201216) ? (ws_size - 201216) : 0;

    // largest chunk (multiple of 16 cols, power of two) fitting in avail
    int chunk = 256;
    while (chunk > 16 && (size_t)N_NODES * chunk * sizeof(float) > avail) chunk >>= 1;

    // d_out layout: z [N*47] | y_pred [N*47] | S1 [N*256] | S2 [N*256]
    float* z     = (float*)d_out;
    float* ypred = z + (long long)N_NODES * D_OUT;
    float* S1    = ypred + (long long)N_NODES * D_OUT;
    float* S2    = S1 + (long long)N_NODES * D_HID;

    // --- edge layout detect + degrees ---
    detect_idx_kernel<<<1, 256, 0, stream>>>(ei, flag);
    hipMemsetAsync(deg, 0, N_NODES * sizeof(float), stream);
    deg_kernel<<<(N_EDGES + 255) / 256, 256, 0, stream>>>(ei, flag, deg);
    inv_deg_kernel<<<(N_NODES + 255) / 256, 256, 0, stream>>>(deg);

    // --- three SAGE layers ---
    run_layer(x,  D_IN,  W1_l, W1_r, b1, bn1_g, bn1_b, bn1_m, bn1_v, S1, D_HID, 1,
              chunk, agg, deg, ei, flag, stream);
    run_layer(S1, D_HID, W2_l, W2_r, b2, bn2_g, bn2_b, bn2_m, bn2_v, S2, D_HID, 1,
              chunk, agg, deg, ei, flag, stream);
    run_layer(S2, D_HID, W3_l, W3_r, b3, nullptr, nullptr, nullptr, nullptr, z, D_OUT, 0,
              chunk, agg, deg, ei, flag, stream);

    // --- log_softmax ---
    log_softmax_kernel<<<((long long)N_NODES * 64 + 255) / 256, 256, 0, stream>>>(z, ypred);
}

// Round 3
// 1075.118 us; speedup vs baseline: 6.8413x; 6.8413x over previous
//
#include <hip/hip_runtime.h>
#include <cmath>

#define N_NODES 50000
#define N_EDGES 800000
#define D_IN    128
#define D_HID   256
#define D_OUT   47
#define BN_EPS  1e-5f

// ---------------------------------------------------------------------------
// edge_index layout detection (int64 vs int32), runtime, device-side.
// ---------------------------------------------------------------------------
__global__ void detect_idx_kernel(const int* __restrict__ ei, int* __restrict__ flag) {
    __shared__ int any_nonzero;
    if (threadIdx.x == 0) any_nonzero = 0;
    __syncthreads();
    int v = ei[2 * threadIdx.x + 1];
    if (v != 0) atomicAdd(&any_nonzero, 1);
    __syncthreads();
    if (threadIdx.x == 0) *flag = (any_nonzero == 0) ? 1 : 0;
}

__device__ __forceinline__ int load_edge(const int* __restrict__ ei, int e, int which, int is64) {
    if (is64) return ei[2 * ((long long)which * N_EDGES + e)];
    return ei[(long long)which * N_EDGES + e];
}

// ---------------------------------------------------------------------------
// CSR build: degree count -> single-block scan -> cursor fill
// ---------------------------------------------------------------------------
__global__ void count_deg_kernel(const int* __restrict__ ei, const int* __restrict__ flag,
                                 int* __restrict__ degi) {
    int e = blockIdx.x * blockDim.x + threadIdx.x;
    if (e >= N_EDGES) return;
    int is64 = *flag;
    atomicAdd(&degi[load_edge(ei, e, 1, is64)], 1);
}

__global__ __launch_bounds__(1024) void scan_kernel(const int* __restrict__ degi,
                                                    int* __restrict__ row_ptr,
                                                    int* __restrict__ cursor,
                                                    float* __restrict__ invd) {
    const int t = threadIdx.x;
    const int CHUNK = (N_NODES + 1023) / 1024;   // 49
    const int base = t * CHUNK;
    int s = 0;
    for (int i = 0; i < CHUNK; ++i) {
        int idx = base + i;
        if (idx < N_NODES) s += degi[idx];
    }
    __shared__ int sh[1024];
    sh[t] = s;
    __syncthreads();
    for (int off = 1; off < 1024; off <<= 1) {
        int v = (t >= off) ? sh[t - off] : 0;
        __syncthreads();
        sh[t] += v;
        __syncthreads();
    }
    int run = sh[t] - s;   // exclusive prefix
    for (int i = 0; i < CHUNK; ++i) {
        int idx = base + i;
        if (idx < N_NODES) {
            int d = degi[idx];
            row_ptr[idx] = run;
            cursor[idx]  = run;
            invd[idx]    = 1.0f / fmaxf((float)d, 1.0f);
            run += d;
        }
    }
    if (t == 1023) row_ptr[N_NODES] = sh[1023];
}

__global__ void fill_csr_kernel(const int* __restrict__ ei, const int* __restrict__ flag,
                                int* __restrict__ cursor, int* __restrict__ ssrc) {
    int e = blockIdx.x * blockDim.x + threadIdx.x;
    if (e >= N_EDGES) return;
    int is64 = *flag;
    int s = load_edge(ei, e, 0, is64);
    int d = load_edge(ei, e, 1, is64);
    int pos = atomicAdd(&cursor[d], 1);
    ssrc[pos] = s;
}

// ---------------------------------------------------------------------------
// CSR gather-mean: one wave per node; lanes cover CC feature cols.
// agg[n, 0:CC] = mean over incoming src of X[src, c0:c0+CC]
// ---------------------------------------------------------------------------
template <int CC>
__global__ __launch_bounds__(256) void gather_mean(
    const float* __restrict__ X, int ldx, int c0,
    const int* __restrict__ rp, const int* __restrict__ ssrc,
    const float* __restrict__ invd, float* __restrict__ agg)
{
    const long long gid = (long long)blockIdx.x * blockDim.x + threadIdx.x;
    const int w = (int)(gid >> 6);
    const int lane = threadIdx.x & 63;
    if (w >= N_NODES) return;
    const int start = rp[w], end = rp[w + 1];
    const float sc = invd[w];

    if constexpr (CC == 256) {
        const float* base = X + c0 + lane * 4;
        float4 a = make_float4(0.f, 0.f, 0.f, 0.f);
        int e = start;
        for (; e + 1 < end; e += 2) {
            int s0 = ssrc[e], s1 = ssrc[e + 1];
            float4 v0 = *(const float4*)(base + (long long)s0 * ldx);
            float4 v1 = *(const float4*)(base + (long long)s1 * ldx);
            a.x += v0.x + v1.x; a.y += v0.y + v1.y;
            a.z += v0.z + v1.z; a.w += v0.w + v1.w;
        }
        if (e < end) {
            float4 v = *(const float4*)(base + (long long)ssrc[e] * ldx);
            a.x += v.x; a.y += v.y; a.z += v.z; a.w += v.w;
        }
        float4 o = make_float4(a.x * sc, a.y * sc, a.z * sc, a.w * sc);
        *(float4*)(agg + (long long)w * 256 + lane * 4) = o;
    } else if constexpr (CC == 128) {
        const float* base = X + c0 + lane * 2;
        float2 a = make_float2(0.f, 0.f);
        int e = start;
        for (; e + 1 < end; e += 2) {
            int s0 = ssrc[e], s1 = ssrc[e + 1];
            float2 v0 = *(const float2*)(base + (long long)s0 * ldx);
            float2 v1 = *(const float2*)(base + (long long)s1 * ldx);
            a.x += v0.x + v1.x; a.y += v0.y + v1.y;
        }
        if (e < end) {
            float2 v = *(const float2*)(base + (long long)ssrc[e] * ldx);
            a.x += v.x; a.y += v.y;
        }
        float2 o = make_float2(a.x * sc, a.y * sc);
        *(float2*)(agg + (long long)w * 128 + lane * 2) = o;
    } else {  // CC == 64
        const float* base = X + c0 + lane;
        float a = 0.f;
        int e = start;
        for (; e + 1 < end; e += 2) {
            int s0 = ssrc[e], s1 = ssrc[e + 1];
            a += base[(long long)s0 * ldx] + base[(long long)s1 * ldx];
        }
        if (e < end) a += base[(long long)ssrc[e] * ldx];
        agg[(long long)w * 64 + lane] = a * sc;
    }
}

// ---------------------------------------------------------------------------
// layer-3 aggregate (transform-first): z[n, 0:47] += mean over nbrs of U[src, 0:47]
// ---------------------------------------------------------------------------
__global__ __launch_bounds__(256) void gather_add_out(
    const float* __restrict__ U, const int* __restrict__ rp,
    const int* __restrict__ ssrc, const float* __restrict__ invd,
    float* __restrict__ z)
{
    const long long gid = (long long)blockIdx.x * blockDim.x + threadIdx.x;
    const int w = (int)(gid >> 6);
    const int lane = threadIdx.x & 63;
    if (w >= N_NODES) return;
    const int start = rp[w], end = rp[w + 1];
    float a = 0.f;
    for (int e = start; e < end; ++e) {
        int s = ssrc[e];
        if (lane < D_OUT) a += U[(long long)s * D_OUT + lane];
    }
    if (lane < D_OUT) {
        const long long off = (long long)w * D_OUT + lane;
        z[off] += a * invd[w];
    }
}

// ---------------------------------------------------------------------------
// Generalized fused GEMM: C[ldc] = [acc_in? C] + A0@B0 (+ A1@B1) [+bias][+BN+ReLU]
// 64x64 tile, 256 threads, 4x4 micro-tile, BK=16. K multiples of 16.
// ---------------------------------------------------------------------------
#define BM 64
#define BN 64
#define BK 16

__global__ __launch_bounds__(256) void sage_gemm(
    const float* __restrict__ A0, const float* __restrict__ B0, int K0,
    const float* __restrict__ A1, const float* __restrict__ B1, int K1,
    const float* __restrict__ bias,
    const float* __restrict__ gamma, const float* __restrict__ beta,
    const float* __restrict__ mean, const float* __restrict__ var,
    float* __restrict__ C, int ldc, int M,
    int acc_in, int do_bias, int bn_relu)
{
    __shared__ float As[BK][BM + 4];
    __shared__ float Bs[BK][BN + 4];

    const int tid = threadIdx.x;
    const int tx = tid & 15;
    const int ty = tid >> 4;
    const int row0 = blockIdx.y * BM;
    const int col0 = blockIdx.x * BN;

    float acc[4][4];
#pragma unroll
    for (int i = 0; i < 4; ++i)
#pragma unroll
        for (int j = 0; j < 4; ++j) acc[i][j] = 0.0f;

    const int ar = tid >> 2;
    const int ak = (tid & 3) * 4;
    const int bc = tid & 63;
    const int bk = tid >> 6;

    for (int pass = 0; pass < 2; ++pass) {
        if (pass == 1 && A1 == nullptr) break;
        const float* __restrict__ A = pass ? A1 : A0;
        const float* __restrict__ B = pass ? B1 : B0;
        const int K = pass ? K1 : K0;

        for (int k0 = 0; k0 < K; k0 += BK) {
            const int grow = row0 + ar;
            float4 av = make_float4(0.f, 0.f, 0.f, 0.f);
            if (grow < N_NODES)
                av = *(const float4*)(A + (long long)grow * K + k0 + ak);
            As[ak + 0][ar] = av.x;
            As[ak + 1][ar] = av.y;
            As[ak + 2][ar] = av.z;
            As[ak + 3][ar] = av.w;

            const int gcol = col0 + bc;
#pragma unroll
            for (int j = 0; j < 4; ++j) {
                const int krow = k0 + bk + j * 4;
                Bs[bk + j * 4][bc] = (gcol < M) ? B[(long long)krow * M + gcol] : 0.0f;
            }
            __syncthreads();

#pragma unroll
            for (int kk = 0; kk < BK; ++kk) {
                float a[4], b[4];
#pragma unroll
                for (int i = 0; i < 4; ++i) a[i] = As[kk][ty * 4 + i];
#pragma unroll
                for (int j = 0; j < 4; ++j) b[j] = Bs[kk][tx * 4 + j];
#pragma unroll
                for (int i = 0; i < 4; ++i)
#pragma unroll
                    for (int j = 0; j < 4; ++j) acc[i][j] += a[i] * b[j];
            }
            __syncthreads();
        }
    }

#pragma unroll
    for (int i = 0; i < 4; ++i) {
        const int row = row0 + ty * 4 + i;
        if (row >= N_NODES) continue;
#pragma unroll
        for (int j = 0; j < 4; ++j) {
            const int col = col0 + tx * 4 + j;
            if (col >= M) continue;
            const long long off = (long long)row * ldc + col;
            float v = acc[i][j];
            if (acc_in) v += C[off];
            if (do_bias) v += bias[col];
            if (bn_relu) {
                v = (v - mean[col]) * (gamma[col] * rsqrtf(var[col] + BN_EPS)) + beta[col];
                v = fmaxf(v, 0.0f);
            }
            C[off] = v;
        }
    }
}

// ---------------------------------------------------------------------------
// log_softmax over rows of 47 — one wave per row
// ---------------------------------------------------------------------------
__global__ void log_softmax_kernel(const float* __restrict__ z, float* __restrict__ y) {
    const int gtid = blockIdx.x * blockDim.x + threadIdx.x;
    const int row = gtid >> 6;
    const int lane = threadIdx.x & 63;
    if (row >= N_NODES) return;

    const float* zr = z + (long long)row * D_OUT;
    float v = (lane < D_OUT) ? zr[lane] : -INFINITY;

    float m = v;
#pragma unroll
    for (int off = 32; off > 0; off >>= 1) m = fmaxf(m, __shfl_down(m, off));
    m = __shfl(m, 0);

    float ev = (lane < D_OUT) ? expf(v - m) : 0.0f;
    float s = ev;
#pragma unroll
    for (int off = 32; off > 0; off >>= 1) s += __shfl_down(s, off);
    s = __shfl(s, 0);

    if (lane < D_OUT) y[(long long)row * D_OUT + lane] = v - m - logf(s);
}

// ---------------------------------------------------------------------------
// host helpers
// ---------------------------------------------------------------------------
static void launch_gather(int CC, const float* X, int ldx, int c0,
                          const int* rp, const int* ssrc, const float* invd,
                          float* agg, hipStream_t stream) {
    const int blocks = (N_NODES * 64 + 255) / 256;
    if (CC == 256)      gather_mean<256><<<blocks, 256, 0, stream>>>(X, ldx, c0, rp, ssrc, invd, agg);
    else if (CC == 128) gather_mean<128><<<blocks, 256, 0, stream>>>(X, ldx, c0, rp, ssrc, invd, agg);
    else                gather_mean<64><<<blocks, 256, 0, stream>>>(X, ldx, c0, rp, ssrc, invd, agg);
}

static void run_layer(const float* Xin, int K, const float* Wl, const float* Wr,
                      const float* bias, const float* g, const float* b,
                      const float* m, const float* v, float* Cout, int M, int bn_relu,
                      int chunk, float* agg, const int* rp, const int* ssrc,
                      const float* invd, hipStream_t stream)
{
    const int CC = (chunk < K) ? chunk : K;
    const int nch = K / CC;
    const dim3 gGemm((M + BN - 1) / BN, (N_NODES + BM - 1) / BM);

    for (int c = 0; c < nch; ++c) {
        const int c0 = c * CC;
        const int last = (c == nch - 1);
        launch_gather(CC, Xin, K, c0, rp, ssrc, invd, agg, stream);
        sage_gemm<<<gGemm, 256, 0, stream>>>(
            agg, Wl + (long long)c0 * M, CC,
            last ? Xin : nullptr, Wr, K,
            bias, g, b, m, v,
            Cout, M, M,
            (c > 0) ? 1 : 0, last, last ? bn_relu : 0);
    }
}

// ---------------------------------------------------------------------------
// launch
// ---------------------------------------------------------------------------
extern "C" void kernel_launch(void* const* d_in, const int* in_sizes, int n_in,
                              void* d_out, int out_size, void* d_ws, size_t ws_size,
                              hipStream_t stream) {
    const float* x     = (const float*)d_in[0];
    const int*   ei    = (const int*)d_in[1];
    const float* W1_l  = (const float*)d_in[2];
    const float* b1    = (const float*)d_in[3];
    const float* W1_r  = (const float*)d_in[4];
    const float* bn1_g = (const float*)d_in[5];
    const float* bn1_b = (const float*)d_in[6];
    const float* bn1_m = (const float*)d_in[7];
    const float* bn1_v = (const float*)d_in[8];
    const float* W2_l  = (const float*)d_in[9];
    const float* b2    = (const float*)d_in[10];
    const float* W2_r  = (const float*)d_in[11];
    const float* bn2_g = (const float*)d_in[12];
    const float* bn2_b = (const float*)d_in[13];
    const float* bn2_m = (const float*)d_in[14];
    const float* bn2_v = (const float*)d_in[15];
    const float* W3_l  = (const float*)d_in[16];
    const float* b3    = (const float*)d_in[17];
    const float* W3_r  = (const float*)d_in[18];

    // --- workspace layout (strictly within ws_size) ---
    char* ws = (char*)d_ws;
    int*   degi   = (int*)(ws + 0);              // N ints      (200,000 B)
    int*   row_ptr= (int*)(ws + 200704);         // N+1 ints
    int*   cursor = (int*)(ws + 401408);         // N ints
    float* invd   = (float*)(ws + 602112);       // N floats
    int*   flag   = (int*)(ws + 802816);         // 1 int (512 B slot)
    int*   ssrc   = (int*)(ws + 803328);         // E ints      (3,200,000 B)
    float* agg    = (float*)(ws + 4003840);      // adaptive region (also holds U)
    const size_t avail = (ws_size > 4003840) ? ws_size - 4003840 : 0;

    int chunk = 256;
    while (chunk > 64 && (size_t)N_NODES * chunk * sizeof(float) > avail) chunk >>= 1;

    // d_out layout: z [N*47] | y_pred [N*47] | S1 [N*256] | S2 [N*256]
    float* z     = (float*)d_out;
    float* ypred = z + (long long)N_NODES * D_OUT;
    float* S1    = ypred + (long long)N_NODES * D_OUT;
    float* S2    = S1 + (long long)N_NODES * D_HID;
    float* U     = agg;   // N*47 floats, reused after layer-2 agg is done

    // --- CSR build ---
    detect_idx_kernel<<<1, 256, 0, stream>>>(ei, flag);
    hipMemsetAsync(degi, 0, N_NODES * sizeof(int), stream);
    count_deg_kernel<<<(N_EDGES + 255) / 256, 256, 0, stream>>>(ei, flag, degi);
    scan_kernel<<<1, 1024, 0, stream>>>(degi, row_ptr, cursor, invd);
    fill_csr_kernel<<<(N_EDGES + 255) / 256, 256, 0, stream>>>(ei, flag, cursor, ssrc);

    // --- layers 1 & 2 (aggregate-first) ---
    run_layer(x,  D_IN,  W1_l, W1_r, b1, bn1_g, bn1_b, bn1_m, bn1_v, S1, D_HID, 1,
              chunk, agg, row_ptr, ssrc, invd, stream);
    run_layer(S1, D_HID, W2_l, W2_r, b2, bn2_g, bn2_b, bn2_m, bn2_v, S2, D_HID, 1,
              chunk, agg, row_ptr, ssrc, invd, stream);

    // --- layer 3 (transform-first: width-47 aggregation) ---
    const dim3 gOut((D_OUT + BN - 1) / BN, (N_NODES + BM - 1) / BM);
    // U = S2 @ W3_l
    sage_gemm<<<gOut, 256, 0, stream>>>(S2, W3_l, D_HID, nullptr, nullptr, 0,
                                        nullptr, nullptr, nullptr, nullptr, nullptr,
                                        U, D_OUT, D_OUT, 0, 0, 0);
    // z = S2 @ W3_r + b3
    sage_gemm<<<gOut, 256, 0, stream>>>(S2, W3_r, D_HID, nullptr, nullptr, 0,
                                        b3, nullptr, nullptr, nullptr, nullptr,
                                        z, D_OUT, D_OUT, 0, 1, 0);
    // z += mean(U[nbrs])
    gather_add_out<<<(N_NODES * 64 + 255) / 256, 256, 0, stream>>>(U, row_ptr, ssrc, invd, z);

    // --- log_softmax ---
    log_softmax_kernel<<<(N_NODES * 64 + 255) / 256, 256, 0, stream>>>(z, ypred);
}

// Round 4
// 887.200 us; speedup vs baseline: 8.2903x; 1.2118x over previous
//
#include <hip/hip_runtime.h>
#include <cmath>

#define N_NODES 50000
#define N_EDGES 800000
#define D_IN    128
#define D_HID   256
#define D_OUT   47
#define BN_EPS  1e-5f

typedef __attribute__((ext_vector_type(8))) short bf16x8;
typedef __attribute__((ext_vector_type(4))) float floatx4;

__device__ __forceinline__ short f2bf(float f) {
    unsigned u = __float_as_uint(f);
    u += 0x7fff + ((u >> 16) & 1);   // round-to-nearest-even
    return (short)(u >> 16);
}

// ---------------------------------------------------------------------------
// edge_index layout detection (int64 vs int32), runtime, device-side.
// ---------------------------------------------------------------------------
__global__ void detect_idx_kernel(const int* __restrict__ ei, int* __restrict__ flag) {
    __shared__ int any_nonzero;
    if (threadIdx.x == 0) any_nonzero = 0;
    __syncthreads();
    int v = ei[2 * threadIdx.x + 1];
    if (v != 0) atomicAdd(&any_nonzero, 1);
    __syncthreads();
    if (threadIdx.x == 0) *flag = (any_nonzero == 0) ? 1 : 0;
}

__device__ __forceinline__ int load_edge(const int* __restrict__ ei, int e, int which, int is64) {
    if (is64) return ei[2 * ((long long)which * N_EDGES + e)];
    return ei[(long long)which * N_EDGES + e];
}

// ---------------------------------------------------------------------------
// CSR build: degree count -> single-block scan -> cursor fill
// ---------------------------------------------------------------------------
__global__ void count_deg_kernel(const int* __restrict__ ei, const int* __restrict__ flag,
                                 int* __restrict__ degi) {
    int e = blockIdx.x * blockDim.x + threadIdx.x;
    if (e >= N_EDGES) return;
    int is64 = *flag;
    atomicAdd(&degi[load_edge(ei, e, 1, is64)], 1);
}

__global__ __launch_bounds__(1024) void scan_kernel(const int* __restrict__ degi,
                                                    int* __restrict__ row_ptr,
                                                    int* __restrict__ cursor,
                                                    float* __restrict__ invd) {
    const int t = threadIdx.x;
    const int CHUNK = (N_NODES + 1023) / 1024;   // 49
    const int base = t * CHUNK;
    int s = 0;
    for (int i = 0; i < CHUNK; ++i) {
        int idx = base + i;
        if (idx < N_NODES) s += degi[idx];
    }
    __shared__ int sh[1024];
    sh[t] = s;
    __syncthreads();
    for (int off = 1; off < 1024; off <<= 1) {
        int v = (t >= off) ? sh[t - off] : 0;
        __syncthreads();
        sh[t] += v;
        __syncthreads();
    }
    int run = sh[t] - s;   // exclusive prefix
    for (int i = 0; i < CHUNK; ++i) {
        int idx = base + i;
        if (idx < N_NODES) {
            int d = degi[idx];
            row_ptr[idx] = run;
            cursor[idx]  = run;
            invd[idx]    = 1.0f / fmaxf((float)d, 1.0f);
            run += d;
        }
    }
    if (t == 1023) row_ptr[N_NODES] = sh[1023];
}

__global__ void fill_csr_kernel(const int* __restrict__ ei, const int* __restrict__ flag,
                                int* __restrict__ cursor, int* __restrict__ ssrc) {
    int e = blockIdx.x * blockDim.x + threadIdx.x;
    if (e >= N_EDGES) return;
    int is64 = *flag;
    int s = load_edge(ei, e, 0, is64);
    int d = load_edge(ei, e, 1, is64);
    int pos = atomicAdd(&cursor[d], 1);
    ssrc[pos] = s;
}

// ---------------------------------------------------------------------------
// CSR gather-mean: one wave per node; lanes cover CC feature cols.
// ---------------------------------------------------------------------------
template <int CC>
__global__ __launch_bounds__(256) void gather_mean(
    const float* __restrict__ X, int ldx,
    const int* __restrict__ rp, const int* __restrict__ ssrc,
    const float* __restrict__ invd, float* __restrict__ agg)
{
    const long long gid = (long long)blockIdx.x * blockDim.x + threadIdx.x;
    const int w = (int)(gid >> 6);
    const int lane = threadIdx.x & 63;
    if (w >= N_NODES) return;
    const int start = rp[w], end = rp[w + 1];
    const float sc = invd[w];

    if constexpr (CC == 256) {
        const float* base = X + lane * 4;
        float4 a = make_float4(0.f, 0.f, 0.f, 0.f);
        int e = start;
        for (; e + 1 < end; e += 2) {
            int s0 = ssrc[e], s1 = ssrc[e + 1];
            float4 v0 = *(const float4*)(base + (long long)s0 * ldx);
            float4 v1 = *(const float4*)(base + (long long)s1 * ldx);
            a.x += v0.x + v1.x; a.y += v0.y + v1.y;
            a.z += v0.z + v1.z; a.w += v0.w + v1.w;
        }
        if (e < end) {
            float4 v = *(const float4*)(base + (long long)ssrc[e] * ldx);
            a.x += v.x; a.y += v.y; a.z += v.z; a.w += v.w;
        }
        float4 o = make_float4(a.x * sc, a.y * sc, a.z * sc, a.w * sc);
        *(float4*)(agg + (long long)w * 256 + lane * 4) = o;
    } else {  // CC == 128
        const float* base = X + lane * 2;
        float2 a = make_float2(0.f, 0.f);
        int e = start;
        for (; e + 1 < end; e += 2) {
            int s0 = ssrc[e], s1 = ssrc[e + 1];
            float2 v0 = *(const float2*)(base + (long long)s0 * ldx);
            float2 v1 = *(const float2*)(base + (long long)s1 * ldx);
            a.x += v0.x + v1.x; a.y += v0.y + v1.y;
        }
        if (e < end) {
            float2 v = *(const float2*)(base + (long long)ssrc[e] * ldx);
            a.x += v.x; a.y += v.y;
        }
        float2 o = make_float2(a.x * sc, a.y * sc);
        *(float2*)(agg + (long long)w * 128 + lane * 2) = o;
    }
}

// ---------------------------------------------------------------------------
// layer-3 aggregate (transform-first): z[n,0:47] += mean over nbrs of U[src,0:47]
// ---------------------------------------------------------------------------
__global__ __launch_bounds__(256) void gather_add_out(
    const float* __restrict__ U, const int* __restrict__ rp,
    const int* __restrict__ ssrc, const float* __restrict__ invd,
    float* __restrict__ z)
{
    const long long gid = (long long)blockIdx.x * blockDim.x + threadIdx.x;
    const int w = (int)(gid >> 6);
    const int lane = threadIdx.x & 63;
    if (w >= N_NODES) return;
    const int start = rp[w], end = rp[w + 1];
    float a = 0.f;
    for (int e = start; e < end; ++e) {
        int s = ssrc[e];
        if (lane < D_OUT) a += U[(long long)s * D_OUT + lane];
    }
    if (lane < D_OUT) {
        const long long off = (long long)w * D_OUT + lane;
        z[off] += a * invd[w];
    }
}

// ---------------------------------------------------------------------------
// bf16 MFMA GEMM:  C = A0@B0 (+ A1@B1) [+bias] [+BN+ReLU]
// Operands fp32 in HBM; staging converts to bf16 (RNE) into LDS.
// Tile 128x64x32, 256 threads = 4 waves, per-wave 2x4 tiles of 16x16x32.
// A LDS: [row][k] stride 40 shorts; B LDS transposed: [col][k] stride 40.
// Fragment layout (measured m89/m91): A/B lane l -> m/n = l&15, k = (l>>4)*8+j
// C/D: col = lane&15, row = (lane>>4)*4 + reg.
// Requires K multiple of 32.
// ---------------------------------------------------------------------------
#define GBM 128
#define GBN 64
#define GBK 32
#define LDA 40
#define LDB 40

__global__ __launch_bounds__(256) void mfma_gemm(
    const float* __restrict__ A0, const float* __restrict__ B0, int K0,
    const float* __restrict__ A1, const float* __restrict__ B1, int K1,
    const float* __restrict__ bias,
    const float* __restrict__ gamma, const float* __restrict__ beta,
    const float* __restrict__ mean, const float* __restrict__ var,
    float* __restrict__ C, int M, int do_bias, int bn_relu)
{
    __shared__ short As[GBM * LDA];
    __shared__ short Bs[GBN * LDB];

    const int t = threadIdx.x;
    const int wv = t >> 6;
    const int lane = t & 63;
    const int row0 = blockIdx.y * GBM;
    const int col0 = blockIdx.x * GBN;

    const int lr = lane & 15;            // fragment row/col
    const int lk = (lane >> 4) * 8;      // fragment k base

    floatx4 acc[2][4];
#pragma unroll
    for (int r = 0; r < 2; ++r)
#pragma unroll
        for (int c = 0; c < 4; ++c) acc[r][c] = (floatx4){0.f, 0.f, 0.f, 0.f};

    const int arow = t >> 3;        // 0..31
    const int akc  = (t & 7) * 4;   // 0..28
    const int bkr  = t >> 4;        // 0..15
    const int bcc  = (t & 15) * 4;  // 0..60

    for (int pass = 0; pass < 2; ++pass) {
        if (pass == 1 && A1 == nullptr) break;
        const float* __restrict__ A = pass ? A1 : A0;
        const float* __restrict__ B = pass ? B1 : B0;
        const int K = pass ? K1 : K0;

        for (int k0 = 0; k0 < K; k0 += GBK) {
            __syncthreads();   // protect LDS from previous iteration's readers

            // ---- stage A (128 x 32 fp32 -> bf16) ----
#pragma unroll
            for (int i = 0; i < 4; ++i) {
                const int lrow = arow + i * 32;
                const int grow = row0 + lrow;
                float4 v = make_float4(0.f, 0.f, 0.f, 0.f);
                if (grow < N_NODES)
                    v = *(const float4*)(A + (long long)grow * K + k0 + akc);
                short4 sv;
                sv.x = f2bf(v.x); sv.y = f2bf(v.y);
                sv.z = f2bf(v.z); sv.w = f2bf(v.w);
                *(short4*)(&As[lrow * LDA + akc]) = sv;
            }

            // ---- stage B (32 x 64 fp32 -> bf16, transposed to [col][k]) ----
#pragma unroll
            for (int i = 0; i < 2; ++i) {
                const int k = bkr + i * 16;
                const int gc = col0 + bcc;
                float4 v;
                if (gc + 3 < M) {
                    v = *(const float4*)(B + (long long)(k0 + k) * M + gc);
                } else {
                    v.x = (gc + 0 < M) ? B[(long long)(k0 + k) * M + gc + 0] : 0.f;
                    v.y = (gc + 1 < M) ? B[(long long)(k0 + k) * M + gc + 1] : 0.f;
                    v.z = (gc + 2 < M) ? B[(long long)(k0 + k) * M + gc + 2] : 0.f;
                    v.w = (gc + 3 < M) ? B[(long long)(k0 + k) * M + gc + 3] : 0.f;
                }
                Bs[(bcc + 0) * LDB + k] = f2bf(v.x);
                Bs[(bcc + 1) * LDB + k] = f2bf(v.y);
                Bs[(bcc + 2) * LDB + k] = f2bf(v.z);
                Bs[(bcc + 3) * LDB + k] = f2bf(v.w);
            }
            __syncthreads();

            // ---- fragments + MFMA ----
            bf16x8 af[2], bfr[4];
#pragma unroll
            for (int r = 0; r < 2; ++r)
                af[r] = *(const bf16x8*)(&As[(wv * 32 + r * 16 + lr) * LDA + lk]);
#pragma unroll
            for (int c = 0; c < 4; ++c)
                bfr[c] = *(const bf16x8*)(&Bs[(c * 16 + lr) * LDB + lk]);
#pragma unroll
            for (int r = 0; r < 2; ++r)
#pragma unroll
                for (int c = 0; c < 4; ++c)
                    acc[r][c] = __builtin_amdgcn_mfma_f32_16x16x32_bf16(
                        af[r], bfr[c], acc[r][c], 0, 0, 0);
        }
    }

    // ---- epilogue ----
#pragma unroll
    for (int r = 0; r < 2; ++r) {
#pragma unroll
        for (int g = 0; g < 4; ++g) {
            const int row = row0 + wv * 32 + r * 16 + (lane >> 4) * 4 + g;
            if (row >= N_NODES) continue;
#pragma unroll
            for (int c = 0; c < 4; ++c) {
                const int col = col0 + c * 16 + lr;
                if (col >= M) continue;
                float v = acc[r][c][g];
                if (do_bias) v += bias[col];
                if (bn_relu) {
                    v = (v - mean[col]) * (gamma[col] * rsqrtf(var[col] + BN_EPS)) + beta[col];
                    v = fmaxf(v, 0.0f);
                }
                C[(long long)row * M + col] = v;
            }
        }
    }
}

// ---------------------------------------------------------------------------
// log_softmax over rows of 47 — one wave per row
// ---------------------------------------------------------------------------
__global__ void log_softmax_kernel(const float* __restrict__ z, float* __restrict__ y) {
    const int gtid = blockIdx.x * blockDim.x + threadIdx.x;
    const int row = gtid >> 6;
    const int lane = threadIdx.x & 63;
    if (row >= N_NODES) return;

    const float* zr = z + (long long)row * D_OUT;
    float v = (lane < D_OUT) ? zr[lane] : -INFINITY;

    float m = v;
#pragma unroll
    for (int off = 32; off > 0; off >>= 1) m = fmaxf(m, __shfl_down(m, off));
    m = __shfl(m, 0);

    float ev = (lane < D_OUT) ? expf(v - m) : 0.0f;
    float s = ev;
#pragma unroll
    for (int off = 32; off > 0; off >>= 1) s += __shfl_down(s, off);
    s = __shfl(s, 0);

    if (lane < D_OUT) y[(long long)row * D_OUT + lane] = v - m - logf(s);
}

// ---------------------------------------------------------------------------
// launch
// ---------------------------------------------------------------------------
extern "C" void kernel_launch(void* const* d_in, const int* in_sizes, int n_in,
                              void* d_out, int out_size, void* d_ws, size_t ws_size,
                              hipStream_t stream) {
    const float* x     = (const float*)d_in[0];
    const int*   ei    = (const int*)d_in[1];
    const float* W1_l  = (const float*)d_in[2];
    const float* b1    = (const float*)d_in[3];
    const float* W1_r  = (const float*)d_in[4];
    const float* bn1_g = (const float*)d_in[5];
    const float* bn1_b = (const float*)d_in[6];
    const float* bn1_m = (const float*)d_in[7];
    const float* bn1_v = (const float*)d_in[8];
    const float* W2_l  = (const float*)d_in[9];
    const float* b2    = (const float*)d_in[10];
    const float* W2_r  = (const float*)d_in[11];
    const float* bn2_g = (const float*)d_in[12];
    const float* bn2_b = (const float*)d_in[13];
    const float* bn2_m = (const float*)d_in[14];
    const float* bn2_v = (const float*)d_in[15];
    const float* W3_l  = (const float*)d_in[16];
    const float* b3    = (const float*)d_in[17];
    const float* W3_r  = (const float*)d_in[18];

    // --- workspace layout (same as R3; proven to fit) ---
    char* ws = (char*)d_ws;
    int*   degi    = (int*)(ws + 0);
    int*   row_ptr = (int*)(ws + 200704);
    int*   cursor  = (int*)(ws + 401408);
    float* invd    = (float*)(ws + 602112);
    int*   flag    = (int*)(ws + 802816);
    int*   ssrc    = (int*)(ws + 803328);
    float* agg     = (float*)(ws + 4003840);   // N*256 fp32 max; U reuses this

    // d_out layout: z [N*47] | y_pred [N*47] | S1 [N*256] | S2 [N*256]
    float* z     = (float*)d_out;
    float* ypred = z + (long long)N_NODES * D_OUT;
    float* S1    = ypred + (long long)N_NODES * D_OUT;
    float* S2    = S1 + (long long)N_NODES * D_HID;
    float* U     = agg;   // N*47 fp32, reused after layer-2 agg consumed

    // --- CSR build ---
    detect_idx_kernel<<<1, 256, 0, stream>>>(ei, flag);
    hipMemsetAsync(degi, 0, N_NODES * sizeof(int), stream);
    count_deg_kernel<<<(N_EDGES + 255) / 256, 256, 0, stream>>>(ei, flag, degi);
    scan_kernel<<<1, 1024, 0, stream>>>(degi, row_ptr, cursor, invd);
    fill_csr_kernel<<<(N_EDGES + 255) / 256, 256, 0, stream>>>(ei, flag, cursor, ssrc);

    const int gblocks = (N_NODES * 64 + 255) / 256;
    const dim3 gHid(D_HID / GBN, (N_NODES + GBM - 1) / GBM);   // 4 x 391
    const dim3 gOut(1, (N_NODES + GBM - 1) / GBM);             // 1 x 391

    // --- layer 1 ---
    gather_mean<128><<<gblocks, 256, 0, stream>>>(x, D_IN, row_ptr, ssrc, invd, agg);
    mfma_gemm<<<gHid, 256, 0, stream>>>(agg, W1_l, D_IN, x, W1_r, D_IN,
                                        b1, bn1_g, bn1_b, bn1_m, bn1_v,
                                        S1, D_HID, 1, 1);

    // --- layer 2 ---
    gather_mean<256><<<gblocks, 256, 0, stream>>>(S1, D_HID, row_ptr, ssrc, invd, agg);
    mfma_gemm<<<gHid, 256, 0, stream>>>(agg, W2_l, D_HID, S1, W2_r, D_HID,
                                        b2, bn2_g, bn2_b, bn2_m, bn2_v,
                                        S2, D_HID, 1, 1);

    // --- layer 3 (transform-first) ---
    mfma_gemm<<<gOut, 256, 0, stream>>>(S2, W3_l, D_HID, nullptr, nullptr, 0,
                                        nullptr, nullptr, nullptr, nullptr, nullptr,
                                        U, D_OUT, 0, 0);
    mfma_gemm<<<gOut, 256, 0, stream>>>(S2, W3_r, D_HID, nullptr, nullptr, 0,
                                        b3, nullptr, nullptr, nullptr, nullptr,
                                        z, D_OUT, 1, 0);
    gather_add_out<<<gblocks, 256, 0, stream>>>(U, row_ptr, ssrc, invd, z);

    // --- log_softmax ---
    log_softmax_kernel<<<gblocks, 256, 0, stream>>>(z, ypred);
}

// Round 5
// 762.732 us; speedup vs baseline: 9.6432x; 1.1632x over previous
//
#include <hip/hip_runtime.h>
#include <cmath>

#define N_NODES 50000
#define N_EDGES 800000
#define D_IN    128
#define D_HID   256
#define D_OUT   47
#define BN_EPS  1e-5f

#define SCAN_NBLK ((N_NODES + 255) / 256)   // 196

typedef __attribute__((ext_vector_type(8))) short bf16x8;
typedef __attribute__((ext_vector_type(4))) float floatx4;

__device__ __forceinline__ short f2bf(float f) {
    unsigned u = __float_as_uint(f);
    u += 0x7fff + ((u >> 16) & 1);   // round-to-nearest-even
    return (short)(u >> 16);
}

// ---------------------------------------------------------------------------
// edge_index layout detection (int64 vs int32), runtime, device-side.
// ---------------------------------------------------------------------------
__global__ void detect_idx_kernel(const int* __restrict__ ei, int* __restrict__ flag) {
    __shared__ int any_nonzero;
    if (threadIdx.x == 0) any_nonzero = 0;
    __syncthreads();
    int v = ei[2 * threadIdx.x + 1];
    if (v != 0) atomicAdd(&any_nonzero, 1);
    __syncthreads();
    if (threadIdx.x == 0) *flag = (any_nonzero == 0) ? 1 : 0;
}

__device__ __forceinline__ int load_edge(const int* __restrict__ ei, int e, int which, int is64) {
    if (is64) return ei[2 * ((long long)which * N_EDGES + e)];
    return ei[(long long)which * N_EDGES + e];
}

// ---------------------------------------------------------------------------
// CSR build: degree count -> hierarchical scan -> cursor fill
// ---------------------------------------------------------------------------
__global__ void count_deg_kernel(const int* __restrict__ ei, const int* __restrict__ flag,
                                 int* __restrict__ degi) {
    int e = blockIdx.x * blockDim.x + threadIdx.x;
    if (e >= N_EDGES) return;
    int is64 = *flag;
    atomicAdd(&degi[load_edge(ei, e, 1, is64)], 1);
}

// per-block sum of 256 degree entries
__global__ __launch_bounds__(256) void block_sum_kernel(const int* __restrict__ degi,
                                                        int* __restrict__ bsum) {
    const int i = blockIdx.x * 256 + threadIdx.x;
    int v = (i < N_NODES) ? degi[i] : 0;
#pragma unroll
    for (int off = 32; off > 0; off >>= 1) v += __shfl_down(v, off);
    __shared__ int sh[4];
    if ((threadIdx.x & 63) == 0) sh[threadIdx.x >> 6] = v;
    __syncthreads();
    if (threadIdx.x == 0) bsum[blockIdx.x] = sh[0] + sh[1] + sh[2] + sh[3];
}

// single block: exclusive scan of the 196 block sums (in-place -> offsets)
__global__ __launch_bounds__(256) void scan_bsums_kernel(int* __restrict__ bsum,
                                                         int* __restrict__ row_ptr) {
    const int t = threadIdx.x;
    __shared__ int sh[256];
    int v = (t < SCAN_NBLK) ? bsum[t] : 0;
    sh[t] = v;
    __syncthreads();
#pragma unroll
    for (int off = 1; off < 256; off <<= 1) {
        int u = (t >= off) ? sh[t - off] : 0;
        __syncthreads();
        sh[t] += u;
        __syncthreads();
    }
    if (t < SCAN_NBLK) bsum[t] = sh[t] - v;            // exclusive prefix
    if (t == 255) row_ptr[N_NODES] = sh[255];          // total (= E)
}

// per-block local exclusive scan + block offset -> row_ptr / cursor / invd
__global__ __launch_bounds__(256) void fill_rowptr_kernel(const int* __restrict__ degi,
                                                          const int* __restrict__ bsum,
                                                          int* __restrict__ row_ptr,
                                                          int* __restrict__ cursor,
                                                          float* __restrict__ invd) {
    const int t = threadIdx.x;
    const int i = blockIdx.x * 256 + t;
    __shared__ int sh[256];
    int d = (i < N_NODES) ? degi[i] : 0;
    sh[t] = d;
    __syncthreads();
#pragma unroll
    for (int off = 1; off < 256; off <<= 1) {
        int u = (t >= off) ? sh[t - off] : 0;
        __syncthreads();
        sh[t] += u;
        __syncthreads();
    }
    if (i < N_NODES) {
        const int pos = bsum[blockIdx.x] + sh[t] - d;  // exclusive
        row_ptr[i] = pos;
        cursor[i]  = pos;
        invd[i]    = 1.0f / fmaxf((float)d, 1.0f);
    }
}

__global__ void fill_csr_kernel(const int* __restrict__ ei, const int* __restrict__ flag,
                                int* __restrict__ cursor, int* __restrict__ ssrc) {
    int e = blockIdx.x * blockDim.x + threadIdx.x;
    if (e >= N_EDGES) return;
    int is64 = *flag;
    int s = load_edge(ei, e, 0, is64);
    int d = load_edge(ei, e, 1, is64);
    int pos = atomicAdd(&cursor[d], 1);
    ssrc[pos] = s;
}

// ---------------------------------------------------------------------------
// CSR gather-mean: one wave per node; lanes cover CC feature cols.
// ---------------------------------------------------------------------------
template <int CC>
__global__ __launch_bounds__(256) void gather_mean(
    const float* __restrict__ X, int ldx,
    const int* __restrict__ rp, const int* __restrict__ ssrc,
    const float* __restrict__ invd, float* __restrict__ agg)
{
    const long long gid = (long long)blockIdx.x * blockDim.x + threadIdx.x;
    const int w = (int)(gid >> 6);
    const int lane = threadIdx.x & 63;
    if (w >= N_NODES) return;
    const int start = rp[w], end = rp[w + 1];
    const float sc = invd[w];

    if constexpr (CC == 256) {
        const float* base = X + lane * 4;
        float4 a = make_float4(0.f, 0.f, 0.f, 0.f);
        int e = start;
        for (; e + 1 < end; e += 2) {
            int s0 = ssrc[e], s1 = ssrc[e + 1];
            float4 v0 = *(const float4*)(base + (long long)s0 * ldx);
            float4 v1 = *(const float4*)(base + (long long)s1 * ldx);
            a.x += v0.x + v1.x; a.y += v0.y + v1.y;
            a.z += v0.z + v1.z; a.w += v0.w + v1.w;
        }
        if (e < end) {
            float4 v = *(const float4*)(base + (long long)ssrc[e] * ldx);
            a.x += v.x; a.y += v.y; a.z += v.z; a.w += v.w;
        }
        float4 o = make_float4(a.x * sc, a.y * sc, a.z * sc, a.w * sc);
        *(float4*)(agg + (long long)w * 256 + lane * 4) = o;
    } else {  // CC == 128
        const float* base = X + lane * 2;
        float2 a = make_float2(0.f, 0.f);
        int e = start;
        for (; e + 1 < end; e += 2) {
            int s0 = ssrc[e], s1 = ssrc[e + 1];
            float2 v0 = *(const float2*)(base + (long long)s0 * ldx);
            float2 v1 = *(const float2*)(base + (long long)s1 * ldx);
            a.x += v0.x + v1.x; a.y += v0.y + v1.y;
        }
        if (e < end) {
            float2 v = *(const float2*)(base + (long long)ssrc[e] * ldx);
            a.x += v.x; a.y += v.y;
        }
        float2 o = make_float2(a.x * sc, a.y * sc);
        *(float2*)(agg + (long long)w * 128 + lane * 2) = o;
    }
}

// ---------------------------------------------------------------------------
// layer-3 aggregate (transform-first): z[n,0:47] += mean over nbrs of U[src,0:47]
// ---------------------------------------------------------------------------
__global__ __launch_bounds__(256) void gather_add_out(
    const float* __restrict__ U, const int* __restrict__ rp,
    const int* __restrict__ ssrc, const float* __restrict__ invd,
    float* __restrict__ z)
{
    const long long gid = (long long)blockIdx.x * blockDim.x + threadIdx.x;
    const int w = (int)(gid >> 6);
    const int lane = threadIdx.x & 63;
    if (w >= N_NODES) return;
    const int start = rp[w], end = rp[w + 1];
    float a = 0.f;
    for (int e = start; e < end; ++e) {
        int s = ssrc[e];
        if (lane < D_OUT) a += U[(long long)s * D_OUT + lane];
    }
    if (lane < D_OUT) {
        const long long off = (long long)w * D_OUT + lane;
        z[off] += a * invd[w];
    }
}

// ---------------------------------------------------------------------------
// bf16 MFMA GEMM:  C = A0@B0 (+ A1@B1) [+bias] [+BN+ReLU]
// Tile 128x64x32, 256 threads = 4 waves, per-wave 2x4 tiles of 16x16x32.
// ---------------------------------------------------------------------------
#define GBM 128
#define GBN 64
#define GBK 32
#define LDA 40
#define LDB 40

__global__ __launch_bounds__(256) void mfma_gemm(
    const float* __restrict__ A0, const float* __restrict__ B0, int K0,
    const float* __restrict__ A1, const float* __restrict__ B1, int K1,
    const float* __restrict__ bias,
    const float* __restrict__ gamma, const float* __restrict__ beta,
    const float* __restrict__ mean, const float* __restrict__ var,
    float* __restrict__ C, int M, int do_bias, int bn_relu)
{
    __shared__ short As[GBM * LDA];
    __shared__ short Bs[GBN * LDB];

    const int t = threadIdx.x;
    const int wv = t >> 6;
    const int lane = t & 63;
    const int row0 = blockIdx.y * GBM;
    const int col0 = blockIdx.x * GBN;

    const int lr = lane & 15;
    const int lk = (lane >> 4) * 8;

    floatx4 acc[2][4];
#pragma unroll
    for (int r = 0; r < 2; ++r)
#pragma unroll
        for (int c = 0; c < 4; ++c) acc[r][c] = (floatx4){0.f, 0.f, 0.f, 0.f};

    const int arow = t >> 3;
    const int akc  = (t & 7) * 4;
    const int bkr  = t >> 4;
    const int bcc  = (t & 15) * 4;

    for (int pass = 0; pass < 2; ++pass) {
        if (pass == 1 && A1 == nullptr) break;
        const float* __restrict__ A = pass ? A1 : A0;
        const float* __restrict__ B = pass ? B1 : B0;
        const int K = pass ? K1 : K0;

        for (int k0 = 0; k0 < K; k0 += GBK) {
            __syncthreads();

            // ---- stage A (128 x 32 fp32 -> bf16) ----
#pragma unroll
            for (int i = 0; i < 4; ++i) {
                const int lrow = arow + i * 32;
                const int grow = row0 + lrow;
                float4 v = make_float4(0.f, 0.f, 0.f, 0.f);
                if (grow < N_NODES)
                    v = *(const float4*)(A + (long long)grow * K + k0 + akc);
                short4 sv;
                sv.x = f2bf(v.x); sv.y = f2bf(v.y);
                sv.z = f2bf(v.z); sv.w = f2bf(v.w);
                *(short4*)(&As[lrow * LDA + akc]) = sv;
            }

            // ---- stage B (32 x 64 fp32 -> bf16, transposed to [col][k]) ----
#pragma unroll
            for (int i = 0; i < 2; ++i) {
                const int k = bkr + i * 16;
                const int gc = col0 + bcc;
                float4 v;
                if (gc + 3 < M) {
                    v = *(const float4*)(B + (long long)(k0 + k) * M + gc);
                } else {
                    v.x = (gc + 0 < M) ? B[(long long)(k0 + k) * M + gc + 0] : 0.f;
                    v.y = (gc + 1 < M) ? B[(long long)(k0 + k) * M + gc + 1] : 0.f;
                    v.z = (gc + 2 < M) ? B[(long long)(k0 + k) * M + gc + 2] : 0.f;
                    v.w = (gc + 3 < M) ? B[(long long)(k0 + k) * M + gc + 3] : 0.f;
                }
                Bs[(bcc + 0) * LDB + k] = f2bf(v.x);
                Bs[(bcc + 1) * LDB + k] = f2bf(v.y);
                Bs[(bcc + 2) * LDB + k] = f2bf(v.z);
                Bs[(bcc + 3) * LDB + k] = f2bf(v.w);
            }
            __syncthreads();

            // ---- fragments + MFMA ----
            bf16x8 af[2], bfr[4];
#pragma unroll
            for (int r = 0; r < 2; ++r)
                af[r] = *(const bf16x8*)(&As[(wv * 32 + r * 16 + lr) * LDA + lk]);
#pragma unroll
            for (int c = 0; c < 4; ++c)
                bfr[c] = *(const bf16x8*)(&Bs[(c * 16 + lr) * LDB + lk]);
#pragma unroll
            for (int r = 0; r < 2; ++r)
#pragma unroll
                for (int c = 0; c < 4; ++c)
                    acc[r][c] = __builtin_amdgcn_mfma_f32_16x16x32_bf16(
                        af[r], bfr[c], acc[r][c], 0, 0, 0);
        }
    }

    // ---- epilogue ----
#pragma unroll
    for (int r = 0; r < 2; ++r) {
#pragma unroll
        for (int g = 0; g < 4; ++g) {
            const int row = row0 + wv * 32 + r * 16 + (lane >> 4) * 4 + g;
            if (row >= N_NODES) continue;
#pragma unroll
            for (int c = 0; c < 4; ++c) {
                const int col = col0 + c * 16 + lr;
                if (col >= M) continue;
                float v = acc[r][c][g];
                if (do_bias) v += bias[col];
                if (bn_relu) {
                    v = (v - mean[col]) * (gamma[col] * rsqrtf(var[col] + BN_EPS)) + beta[col];
                    v = fmaxf(v, 0.0f);
                }
                C[(long long)row * M + col] = v;
            }
        }
    }
}

// ---------------------------------------------------------------------------
// log_softmax over rows of 47 — one wave per row
// ---------------------------------------------------------------------------
__global__ void log_softmax_kernel(const float* __restrict__ z, float* __restrict__ y) {
    const int gtid = blockIdx.x * blockDim.x + threadIdx.x;
    const int row = gtid >> 6;
    const int lane = threadIdx.x & 63;
    if (row >= N_NODES) return;

    const float* zr = z + (long long)row * D_OUT;
    float v = (lane < D_OUT) ? zr[lane] : -INFINITY;

    float m = v;
#pragma unroll
    for (int off = 32; off > 0; off >>= 1) m = fmaxf(m, __shfl_down(m, off));
    m = __shfl(m, 0);

    float ev = (lane < D_OUT) ? expf(v - m) : 0.0f;
    float s = ev;
#pragma unroll
    for (int off = 32; off > 0; off >>= 1) s += __shfl_down(s, off);
    s = __shfl(s, 0);

    if (lane < D_OUT) y[(long long)row * D_OUT + lane] = v - m - logf(s);
}

// ---------------------------------------------------------------------------
// launch
// ---------------------------------------------------------------------------
extern "C" void kernel_launch(void* const* d_in, const int* in_sizes, int n_in,
                              void* d_out, int out_size, void* d_ws, size_t ws_size,
                              hipStream_t stream) {
    const float* x     = (const float*)d_in[0];
    const int*   ei    = (const int*)d_in[1];
    const float* W1_l  = (const float*)d_in[2];
    const float* b1    = (const float*)d_in[3];
    const float* W1_r  = (const float*)d_in[4];
    const float* bn1_g = (const float*)d_in[5];
    const float* bn1_b = (const float*)d_in[6];
    const float* bn1_m = (const float*)d_in[7];
    const float* bn1_v = (const float*)d_in[8];
    const float* W2_l  = (const float*)d_in[9];
    const float* b2    = (const float*)d_in[10];
    const float* W2_r  = (const float*)d_in[11];
    const float* bn2_g = (const float*)d_in[12];
    const float* bn2_b = (const float*)d_in[13];
    const float* bn2_m = (const float*)d_in[14];
    const float* bn2_v = (const float*)d_in[15];
    const float* W3_l  = (const float*)d_in[16];
    const float* b3    = (const float*)d_in[17];
    const float* W3_r  = (const float*)d_in[18];

    // --- workspace layout ---
    char* ws = (char*)d_ws;
    int*   degi    = (int*)(ws + 0);            // N ints
    int*   row_ptr = (int*)(ws + 200704);       // N+1 ints
    int*   cursor  = (int*)(ws + 401408);       // N ints
    float* invd    = (float*)(ws + 602112);     // N floats
    int*   flag    = (int*)(ws + 802816);       // 1 int
    int*   bsum    = (int*)(ws + 802816 + 512); // 196 ints
    int*   ssrc    = (int*)(ws + 803328 + 1024);// E ints  (shifted +1024 for bsum)
    float* agg     = (float*)(ws + 4004864);    // N*256 fp32 max; U reuses this

    // d_out layout: z [N*47] | y_pred [N*47] | S1 [N*256] | S2 [N*256]
    float* z     = (float*)d_out;
    float* ypred = z + (long long)N_NODES * D_OUT;
    float* S1    = ypred + (long long)N_NODES * D_OUT;
    float* S2    = S1 + (long long)N_NODES * D_HID;
    float* U     = agg;

    // --- CSR build (hierarchical scan) ---
    detect_idx_kernel<<<1, 256, 0, stream>>>(ei, flag);
    hipMemsetAsync(degi, 0, N_NODES * sizeof(int), stream);
    count_deg_kernel<<<(N_EDGES + 255) / 256, 256, 0, stream>>>(ei, flag, degi);
    block_sum_kernel<<<SCAN_NBLK, 256, 0, stream>>>(degi, bsum);
    scan_bsums_kernel<<<1, 256, 0, stream>>>(bsum, row_ptr);
    fill_rowptr_kernel<<<SCAN_NBLK, 256, 0, stream>>>(degi, bsum, row_ptr, cursor, invd);
    fill_csr_kernel<<<(N_EDGES + 255) / 256, 256, 0, stream>>>(ei, flag, cursor, ssrc);

    const int gblocks = (N_NODES * 64 + 255) / 256;
    const dim3 gHid(D_HID / GBN, (N_NODES + GBM - 1) / GBM);   // 4 x 391
    const dim3 gOut(1, (N_NODES + GBM - 1) / GBM);             // 1 x 391

    // --- layer 1 ---
    gather_mean<128><<<gblocks, 256, 0, stream>>>(x, D_IN, row_ptr, ssrc, invd, agg);
    mfma_gemm<<<gHid, 256, 0, stream>>>(agg, W1_l, D_IN, x, W1_r, D_IN,
                                        b1, bn1_g, bn1_b, bn1_m, bn1_v,
                                        S1, D_HID, 1, 1);

    // --- layer 2 ---
    gather_mean<256><<<gblocks, 256, 0, stream>>>(S1, D_HID, row_ptr, ssrc, invd, agg);
    mfma_gemm<<<gHid, 256, 0, stream>>>(agg, W2_l, D_HID, S1, W2_r, D_HID,
                                        b2, bn2_g, bn2_b, bn2_m, bn2_v,
                                        S2, D_HID, 1, 1);

    // --- layer 3 (transform-first) ---
    mfma_gemm<<<gOut, 256, 0, stream>>>(S2, W3_l, D_HID, nullptr, nullptr, 0,
                                        nullptr, nullptr, nullptr, nullptr, nullptr,
                                        U, D_OUT, 0, 0);
    mfma_gemm<<<gOut, 256, 0, stream>>>(S2, W3_r, D_HID, nullptr, nullptr, 0,
                                        b3, nullptr, nullptr, nullptr, nullptr,
                                        z, D_OUT, 1, 0);
    gather_add_out<<<gblocks, 256, 0, stream>>>(U, row_ptr, ssrc, invd, z);

    // --- log_softmax ---
    log_softmax_kernel<<<gblocks, 256, 0, stream>>>(z, ypred);
}

// Round 6
// 673.249 us; speedup vs baseline: 10.9249x; 1.1329x over previous
//
#include <hip/hip_runtime.h>
#include <cmath>

#define N_NODES 50000
#define N_EDGES 800000
#define D_IN    128
#define D_HID   256
#define D_OUT   47
#define BN_EPS  1e-5f
#define SCAN_NBLK ((N_NODES + 255) / 256)   // 196

typedef __attribute__((ext_vector_type(8))) short bf16x8;
typedef __attribute__((ext_vector_type(4))) float floatx4;
typedef unsigned short u16;

__device__ __forceinline__ short f2bf(float f) {          // legacy (short)
    unsigned u = __float_as_uint(f);
    u += 0x7fff + ((u >> 16) & 1);
    return (short)(u >> 16);
}
__device__ __forceinline__ u16 f2bf_u(float f) {
    unsigned u = __float_as_uint(f);
    u += 0x7fff + ((u >> 16) & 1);
    return (u16)(u >> 16);
}
__device__ __forceinline__ float bf2f(u16 h) {
    return __uint_as_float(((unsigned)h) << 16);
}

// ---------------------------------------------------------------------------
// edge_index layout detection (int64 vs int32)
// ---------------------------------------------------------------------------
__global__ void detect_idx_kernel(const int* __restrict__ ei, int* __restrict__ flag) {
    __shared__ int any_nonzero;
    if (threadIdx.x == 0) any_nonzero = 0;
    __syncthreads();
    int v = ei[2 * threadIdx.x + 1];
    if (v != 0) atomicAdd(&any_nonzero, 1);
    __syncthreads();
    if (threadIdx.x == 0) *flag = (any_nonzero == 0) ? 1 : 0;
}

__device__ __forceinline__ int load_edge(const int* __restrict__ ei, int e, int which, int is64) {
    if (is64) return ei[2 * ((long long)which * N_EDGES + e)];
    return ei[(long long)which * N_EDGES + e];
}

// ---------------------------------------------------------------------------
// CSR build
// ---------------------------------------------------------------------------
__global__ void count_deg_kernel(const int* __restrict__ ei, const int* __restrict__ flag,
                                 int* __restrict__ degi) {
    int e = blockIdx.x * blockDim.x + threadIdx.x;
    if (e >= N_EDGES) return;
    int is64 = *flag;
    atomicAdd(&degi[load_edge(ei, e, 1, is64)], 1);
}

__global__ __launch_bounds__(256) void block_sum_kernel(const int* __restrict__ degi,
                                                        int* __restrict__ bsum) {
    const int i = blockIdx.x * 256 + threadIdx.x;
    int v = (i < N_NODES) ? degi[i] : 0;
#pragma unroll
    for (int off = 32; off > 0; off >>= 1) v += __shfl_down(v, off);
    __shared__ int sh[4];
    if ((threadIdx.x & 63) == 0) sh[threadIdx.x >> 6] = v;
    __syncthreads();
    if (threadIdx.x == 0) bsum[blockIdx.x] = sh[0] + sh[1] + sh[2] + sh[3];
}

__global__ __launch_bounds__(256) void scan_bsums_kernel(int* __restrict__ bsum,
                                                         int* __restrict__ row_ptr) {
    const int t = threadIdx.x;
    __shared__ int sh[256];
    int v = (t < SCAN_NBLK) ? bsum[t] : 0;
    sh[t] = v;
    __syncthreads();
#pragma unroll
    for (int off = 1; off < 256; off <<= 1) {
        int u = (t >= off) ? sh[t - off] : 0;
        __syncthreads();
        sh[t] += u;
        __syncthreads();
    }
    if (t < SCAN_NBLK) bsum[t] = sh[t] - v;
    if (t == 255) row_ptr[N_NODES] = sh[255];
}

__global__ __launch_bounds__(256) void fill_rowptr_kernel(const int* __restrict__ degi,
                                                          const int* __restrict__ bsum,
                                                          int* __restrict__ row_ptr,
                                                          int* __restrict__ cursor,
                                                          float* __restrict__ invd) {
    const int t = threadIdx.x;
    const int i = blockIdx.x * 256 + t;
    __shared__ int sh[256];
    int d = (i < N_NODES) ? degi[i] : 0;
    sh[t] = d;
    __syncthreads();
#pragma unroll
    for (int off = 1; off < 256; off <<= 1) {
        int u = (t >= off) ? sh[t - off] : 0;
        __syncthreads();
        sh[t] += u;
        __syncthreads();
    }
    if (i < N_NODES) {
        const int pos = bsum[blockIdx.x] + sh[t] - d;
        row_ptr[i] = pos;
        cursor[i]  = pos;
        invd[i]    = 1.0f / fmaxf((float)d, 1.0f);
    }
}

__global__ void fill_csr_kernel(const int* __restrict__ ei, const int* __restrict__ flag,
                                int* __restrict__ cursor, int* __restrict__ ssrc) {
    int e = blockIdx.x * blockDim.x + threadIdx.x;
    if (e >= N_EDGES) return;
    int is64 = *flag;
    int s = load_edge(ei, e, 0, is64);
    int d = load_edge(ei, e, 1, is64);
    int pos = atomicAdd(&cursor[d], 1);
    ssrc[pos] = s;
}

// ===========================================================================
// FULL (bf16-direct) path kernels
// ===========================================================================

// x (fp32) -> xb (bf16), N*128 elems
__global__ void convert_xb_kernel(const float* __restrict__ x, u16* __restrict__ xb) {
    const int n4 = N_NODES * D_IN / 4;
    int i = blockIdx.x * 256 + threadIdx.x;
    if (i >= n4) return;
    float4 v = ((const float4*)x)[i];
    ushort4 o;
    o.x = f2bf_u(v.x); o.y = f2bf_u(v.y); o.z = f2bf_u(v.z); o.w = f2bf_u(v.w);
    ((ushort4*)xb)[i] = o;
}

// all weights -> bf16, transposed to [col][k]; WT3 = [W3_l | W3_r | 0pad] (128x256)
__global__ void build_wt_kernel(const float* __restrict__ W1l, const float* __restrict__ W1r,
                                const float* __restrict__ W2l, const float* __restrict__ W2r,
                                const float* __restrict__ W3l, const float* __restrict__ W3r,
                                u16* __restrict__ wt1l, u16* __restrict__ wt1r,
                                u16* __restrict__ wt2l, u16* __restrict__ wt2r,
                                u16* __restrict__ wt3) {
    int idx = blockIdx.x * 256 + threadIdx.x;
    if (idx < 65536) {                       // WT1l / WT1r : 256 cols x 128 k
        int seg = idx >> 15, d = idx & 32767;
        int c = d >> 7, k = d & 127;
        const float* W = seg ? W1r : W1l;
        u16* WT = seg ? wt1r : wt1l;
        WT[d] = f2bf_u(W[k * 256 + c]);
    } else if (idx < 196608) {               // WT2l / WT2r : 256 cols x 256 k
        int d = idx - 65536;
        int seg = d >> 16; d &= 65535;
        int c = d >> 8, k = d & 255;
        const float* W = seg ? W2r : W2l;
        u16* WT = seg ? wt2r : wt2l;
        WT[d] = f2bf_u(W[k * 256 + c]);
    } else if (idx < 229376) {               // WT3 : 128 cols x 256 k, zero-padded
        int d = idx - 196608;
        int c = d >> 8, k = d & 255;
        float v = 0.f;
        if (c < 47)      v = W3l[k * 47 + c];
        else if (c < 94) v = W3r[k * 47 + (c - 47)];
        wt3[d] = f2bf_u(v);
    }
}

// CSR gather-mean over bf16 rows: one wave per node
template <int CC>
__global__ __launch_bounds__(256) void gather_mean_bf(
    const u16* __restrict__ Xb, const int* __restrict__ rp,
    const int* __restrict__ ssrc, const float* __restrict__ invd,
    u16* __restrict__ agg)
{
    const int w = (blockIdx.x * 256 + threadIdx.x) >> 6;
    const int lane = threadIdx.x & 63;
    if (w >= N_NODES) return;
    const int start = rp[w], end = rp[w + 1];
    const float sc = invd[w];

    if constexpr (CC == 256) {
        const u16* base = Xb + lane * 4;
        float4 a = make_float4(0.f, 0.f, 0.f, 0.f);
        int e = start;
        for (; e + 1 < end; e += 2) {
            const ushort4 v0 = *(const ushort4*)(base + (size_t)ssrc[e] * 256);
            const ushort4 v1 = *(const ushort4*)(base + (size_t)ssrc[e + 1] * 256);
            a.x += bf2f(v0.x) + bf2f(v1.x); a.y += bf2f(v0.y) + bf2f(v1.y);
            a.z += bf2f(v0.z) + bf2f(v1.z); a.w += bf2f(v0.w) + bf2f(v1.w);
        }
        if (e < end) {
            const ushort4 v = *(const ushort4*)(base + (size_t)ssrc[e] * 256);
            a.x += bf2f(v.x); a.y += bf2f(v.y); a.z += bf2f(v.z); a.w += bf2f(v.w);
        }
        ushort4 o;
        o.x = f2bf_u(a.x * sc); o.y = f2bf_u(a.y * sc);
        o.z = f2bf_u(a.z * sc); o.w = f2bf_u(a.w * sc);
        *(ushort4*)(agg + (size_t)w * 256 + lane * 4) = o;
    } else {  // CC == 128
        const u16* base = Xb + lane * 2;
        float2 a = make_float2(0.f, 0.f);
        int e = start;
        for (; e + 1 < end; e += 2) {
            const ushort2 v0 = *(const ushort2*)(base + (size_t)ssrc[e] * 128);
            const ushort2 v1 = *(const ushort2*)(base + (size_t)ssrc[e + 1] * 128);
            a.x += bf2f(v0.x) + bf2f(v1.x); a.y += bf2f(v0.y) + bf2f(v1.y);
        }
        if (e < end) {
            const ushort2 v = *(const ushort2*)(base + (size_t)ssrc[e] * 128);
            a.x += bf2f(v.x); a.y += bf2f(v.y);
        }
        ushort2 o;
        o.x = f2bf_u(a.x * sc); o.y = f2bf_u(a.y * sc);
        *(ushort2*)(agg + (size_t)w * 128 + lane * 2) = o;
    }
}

// ---------------------------------------------------------------------------
// Direct-from-global bf16 MFMA GEMM (no LDS, no barriers):
//   C = A0@WT0^T (+ A1@WT1^T) [+bias][+BN+ReLU], optional bf16 shadow Cb.
//   split>0: cols<split -> C (no bias); split<=col<2*split -> C2 + bias.
// Tile 128x128: 4 waves x 32 rows, 8 col-tiles/wave. K mult of 32.
// A row-major bf16 [N][K]; WT bf16 [col][K].
// ---------------------------------------------------------------------------
__global__ __launch_bounds__(256, 2) void mfma_direct(
    const u16* __restrict__ A0, int K0, const u16* __restrict__ WT0,
    const u16* __restrict__ A1, int K1, const u16* __restrict__ WT1,
    const float* __restrict__ bias,
    const float* __restrict__ gamma, const float* __restrict__ beta,
    const float* __restrict__ mean, const float* __restrict__ var,
    float* __restrict__ C, int M, int do_bias, int bn_relu,
    u16* __restrict__ Cb, float* __restrict__ C2, int split)
{
    const int t = threadIdx.x;
    const int wv = t >> 6, lane = t & 63;
    const int lr = lane & 15, quad = lane >> 4;
    const int row0 = blockIdx.y * 128;
    const int col0 = blockIdx.x * 128;

    floatx4 acc[2][8];
#pragma unroll
    for (int r = 0; r < 2; ++r)
#pragma unroll
        for (int c = 0; c < 8; ++c) acc[r][c] = (floatx4){0.f, 0.f, 0.f, 0.f};

    int rowi[2];
#pragma unroll
    for (int r = 0; r < 2; ++r) {
        int rr = row0 + wv * 32 + r * 16 + lr;
        rowi[r] = (rr < N_NODES) ? rr : (N_NODES - 1);
    }

    for (int pass = 0; pass < 2; ++pass) {
        const u16* __restrict__ A = pass ? A1 : A0;
        if (A == nullptr) break;
        const u16* __restrict__ WT = pass ? WT1 : WT0;
        const int K = pass ? K1 : K0;

        const u16* pa0 = A + (size_t)rowi[0] * K + quad * 8;
        const u16* pa1 = A + (size_t)rowi[1] * K + quad * 8;
        const u16* pb[8];
#pragma unroll
        for (int c = 0; c < 8; ++c)
            pb[c] = WT + (size_t)(col0 + c * 16 + lr) * K + quad * 8;

        for (int k0 = 0; k0 < K; k0 += 32) {
            bf16x8 a0 = *(const bf16x8*)(pa0 + k0);
            bf16x8 a1 = *(const bf16x8*)(pa1 + k0);
            bf16x8 b[8];
#pragma unroll
            for (int c = 0; c < 8; ++c) b[c] = *(const bf16x8*)(pb[c] + k0);
#pragma unroll
            for (int c = 0; c < 8; ++c) {
                acc[0][c] = __builtin_amdgcn_mfma_f32_16x16x32_bf16(a0, b[c], acc[0][c], 0, 0, 0);
                acc[1][c] = __builtin_amdgcn_mfma_f32_16x16x32_bf16(a1, b[c], acc[1][c], 0, 0, 0);
            }
        }
    }

    // epilogue (C/D: col=lr, row=quad*4+g)
#pragma unroll
    for (int r = 0; r < 2; ++r) {
#pragma unroll
        for (int g = 0; g < 4; ++g) {
            const int row = row0 + wv * 32 + r * 16 + quad * 4 + g;
            if (row >= N_NODES) continue;
#pragma unroll
            for (int c = 0; c < 8; ++c) {
                const int col = col0 + c * 16 + lr;
                float v = acc[r][c][g];
                if (split > 0) {
                    if (col < split) {
                        C[(size_t)row * split + col] = v;
                    } else if (col < 2 * split) {
                        C2[(size_t)row * split + (col - split)] = v + bias[col - split];
                    }
                } else {
                    if (col >= M) continue;
                    if (do_bias) v += bias[col];
                    if (bn_relu) {
                        v = (v - mean[col]) * (gamma[col] * rsqrtf(var[col] + BN_EPS)) + beta[col];
                        v = fmaxf(v, 0.0f);
                    }
                    const size_t off = (size_t)row * M + col;
                    C[off] = v;
                    if (Cb) Cb[off] = f2bf_u(v);
                }
            }
        }
    }
}

// ===========================================================================
// SAFE path kernels (R5, proven)
// ===========================================================================
template <int CC>
__global__ __launch_bounds__(256) void gather_mean(
    const float* __restrict__ X, int ldx,
    const int* __restrict__ rp, const int* __restrict__ ssrc,
    const float* __restrict__ invd, float* __restrict__ agg)
{
    const long long gid = (long long)blockIdx.x * blockDim.x + threadIdx.x;
    const int w = (int)(gid >> 6);
    const int lane = threadIdx.x & 63;
    if (w >= N_NODES) return;
    const int start = rp[w], end = rp[w + 1];
    const float sc = invd[w];

    if constexpr (CC == 256) {
        const float* base = X + lane * 4;
        float4 a = make_float4(0.f, 0.f, 0.f, 0.f);
        int e = start;
        for (; e + 1 < end; e += 2) {
            int s0 = ssrc[e], s1 = ssrc[e + 1];
            float4 v0 = *(const float4*)(base + (long long)s0 * ldx);
            float4 v1 = *(const float4*)(base + (long long)s1 * ldx);
            a.x += v0.x + v1.x; a.y += v0.y + v1.y;
            a.z += v0.z + v1.z; a.w += v0.w + v1.w;
        }
        if (e < end) {
            float4 v = *(const float4*)(base + (long long)ssrc[e] * ldx);
            a.x += v.x; a.y += v.y; a.z += v.z; a.w += v.w;
        }
        float4 o = make_float4(a.x * sc, a.y * sc, a.z * sc, a.w * sc);
        *(float4*)(agg + (long long)w * 256 + lane * 4) = o;
    } else {
        const float* base = X + lane * 2;
        float2 a = make_float2(0.f, 0.f);
        int e = start;
        for (; e + 1 < end; e += 2) {
            int s0 = ssrc[e], s1 = ssrc[e + 1];
            float2 v0 = *(const float2*)(base + (long long)s0 * ldx);
            float2 v1 = *(const float2*)(base + (long long)s1 * ldx);
            a.x += v0.x + v1.x; a.y += v0.y + v1.y;
        }
        if (e < end) {
            float2 v = *(const float2*)(base + (long long)ssrc[e] * ldx);
            a.x += v.x; a.y += v.y;
        }
        float2 o = make_float2(a.x * sc, a.y * sc);
        *(float2*)(agg + (long long)w * 128 + lane * 2) = o;
    }
}

#define GBM 128
#define GBN 64
#define GBK 32
#define LDA 40
#define LDB 40

__global__ __launch_bounds__(256) void mfma_gemm(
    const float* __restrict__ A0, const float* __restrict__ B0, int K0,
    const float* __restrict__ A1, const float* __restrict__ B1, int K1,
    const float* __restrict__ bias,
    const float* __restrict__ gamma, const float* __restrict__ beta,
    const float* __restrict__ mean, const float* __restrict__ var,
    float* __restrict__ C, int M, int do_bias, int bn_relu)
{
    __shared__ short As[GBM * LDA];
    __shared__ short Bs[GBN * LDB];

    const int t = threadIdx.x;
    const int wv = t >> 6;
    const int lane = t & 63;
    const int row0 = blockIdx.y * GBM;
    const int col0 = blockIdx.x * GBN;

    const int lr = lane & 15;
    const int lk = (lane >> 4) * 8;

    floatx4 acc[2][4];
#pragma unroll
    for (int r = 0; r < 2; ++r)
#pragma unroll
        for (int c = 0; c < 4; ++c) acc[r][c] = (floatx4){0.f, 0.f, 0.f, 0.f};

    const int arow = t >> 3;
    const int akc  = (t & 7) * 4;
    const int bkr  = t >> 4;
    const int bcc  = (t & 15) * 4;

    for (int pass = 0; pass < 2; ++pass) {
        if (pass == 1 && A1 == nullptr) break;
        const float* __restrict__ A = pass ? A1 : A0;
        const float* __restrict__ B = pass ? B1 : B0;
        const int K = pass ? K1 : K0;

        for (int k0 = 0; k0 < K; k0 += GBK) {
            __syncthreads();
#pragma unroll
            for (int i = 0; i < 4; ++i) {
                const int lrow = arow + i * 32;
                const int grow = row0 + lrow;
                float4 v = make_float4(0.f, 0.f, 0.f, 0.f);
                if (grow < N_NODES)
                    v = *(const float4*)(A + (long long)grow * K + k0 + akc);
                short4 sv;
                sv.x = f2bf(v.x); sv.y = f2bf(v.y);
                sv.z = f2bf(v.z); sv.w = f2bf(v.w);
                *(short4*)(&As[lrow * LDA + akc]) = sv;
            }
#pragma unroll
            for (int i = 0; i < 2; ++i) {
                const int k = bkr + i * 16;
                const int gc = col0 + bcc;
                float4 v;
                if (gc + 3 < M) {
                    v = *(const float4*)(B + (long long)(k0 + k) * M + gc);
                } else {
                    v.x = (gc + 0 < M) ? B[(long long)(k0 + k) * M + gc + 0] : 0.f;
                    v.y = (gc + 1 < M) ? B[(long long)(k0 + k) * M + gc + 1] : 0.f;
                    v.z = (gc + 2 < M) ? B[(long long)(k0 + k) * M + gc + 2] : 0.f;
                    v.w = (gc + 3 < M) ? B[(long long)(k0 + k) * M + gc + 3] : 0.f;
                }
                Bs[(bcc + 0) * LDB + k] = f2bf(v.x);
                Bs[(bcc + 1) * LDB + k] = f2bf(v.y);
                Bs[(bcc + 2) * LDB + k] = f2bf(v.z);
                Bs[(bcc + 3) * LDB + k] = f2bf(v.w);
            }
            __syncthreads();

            bf16x8 af[2], bfr[4];
#pragma unroll
            for (int r = 0; r < 2; ++r)
                af[r] = *(const bf16x8*)(&As[(wv * 32 + r * 16 + lr) * LDA + lk]);
#pragma unroll
            for (int c = 0; c < 4; ++c)
                bfr[c] = *(const bf16x8*)(&Bs[(c * 16 + lr) * LDB + lk]);
#pragma unroll
            for (int r = 0; r < 2; ++r)
#pragma unroll
                for (int c = 0; c < 4; ++c)
                    acc[r][c] = __builtin_amdgcn_mfma_f32_16x16x32_bf16(
                        af[r], bfr[c], acc[r][c], 0, 0, 0);
        }
    }

#pragma unroll
    for (int r = 0; r < 2; ++r) {
#pragma unroll
        for (int g = 0; g < 4; ++g) {
            const int row = row0 + wv * 32 + r * 16 + (lane >> 4) * 4 + g;
            if (row >= N_NODES) continue;
#pragma unroll
            for (int c = 0; c < 4; ++c) {
                const int col = col0 + c * 16 + lr;
                if (col >= M) continue;
                float v = acc[r][c][g];
                if (do_bias) v += bias[col];
                if (bn_relu) {
                    v = (v - mean[col]) * (gamma[col] * rsqrtf(var[col] + BN_EPS)) + beta[col];
                    v = fmaxf(v, 0.0f);
                }
                C[(long long)row * M + col] = v;
            }
        }
    }
}

// ---------------------------------------------------------------------------
// shared epilogue kernels
// ---------------------------------------------------------------------------
__global__ __launch_bounds__(256) void gather_add_out(
    const float* __restrict__ U, const int* __restrict__ rp,
    const int* __restrict__ ssrc, const float* __restrict__ invd,
    float* __restrict__ z)
{
    const int w = (blockIdx.x * 256 + threadIdx.x) >> 6;
    const int lane = threadIdx.x & 63;
    if (w >= N_NODES) return;
    const int start = rp[w], end = rp[w + 1];
    float a = 0.f;
    for (int e = start; e < end; ++e) {
        int s = ssrc[e];
        if (lane < D_OUT) a += U[(long long)s * D_OUT + lane];
    }
    if (lane < D_OUT) z[(long long)w * D_OUT + lane] += a * invd[w];
}

__global__ void log_softmax_kernel(const float* __restrict__ z, float* __restrict__ y) {
    const int gtid = blockIdx.x * blockDim.x + threadIdx.x;
    const int row = gtid >> 6;
    const int lane = threadIdx.x & 63;
    if (row >= N_NODES) return;

    const float* zr = z + (long long)row * D_OUT;
    float v = (lane < D_OUT) ? zr[lane] : -INFINITY;

    float m = v;
#pragma unroll
    for (int off = 32; off > 0; off >>= 1) m = fmaxf(m, __shfl_down(m, off));
    m = __shfl(m, 0);

    float ev = (lane < D_OUT) ? expf(v - m) : 0.0f;
    float s = ev;
#pragma unroll
    for (int off = 32; off > 0; off >>= 1) s += __shfl_down(s, off);
    s = __shfl(s, 0);

    if (lane < D_OUT) y[(long long)row * D_OUT + lane] = v - m - logf(s);
}

// ---------------------------------------------------------------------------
// launch
// ---------------------------------------------------------------------------
extern "C" void kernel_launch(void* const* d_in, const int* in_sizes, int n_in,
                              void* d_out, int out_size, void* d_ws, size_t ws_size,
                              hipStream_t stream) {
    const float* x     = (const float*)d_in[0];
    const int*   ei    = (const int*)d_in[1];
    const float* W1_l  = (const float*)d_in[2];
    const float* b1    = (const float*)d_in[3];
    const float* W1_r  = (const float*)d_in[4];
    const float* bn1_g = (const float*)d_in[5];
    const float* bn1_b = (const float*)d_in[6];
    const float* bn1_m = (const float*)d_in[7];
    const float* bn1_v = (const float*)d_in[8];
    const float* W2_l  = (const float*)d_in[9];
    const float* b2    = (const float*)d_in[10];
    const float* W2_r  = (const float*)d_in[11];
    const float* bn2_g = (const float*)d_in[12];
    const float* bn2_b = (const float*)d_in[13];
    const float* bn2_m = (const float*)d_in[14];
    const float* bn2_v = (const float*)d_in[15];
    const float* W3_l  = (const float*)d_in[16];
    const float* b3    = (const float*)d_in[17];
    const float* W3_r  = (const float*)d_in[18];

    // --- common workspace (CSR) ---
    char* ws = (char*)d_ws;
    int*   degi    = (int*)(ws + 0);
    int*   row_ptr = (int*)(ws + 200064);
    int*   cursor  = (int*)(ws + 400128);
    float* invd    = (float*)(ws + 600192);
    int*   flag    = (int*)(ws + 800256);
    int*   bsum    = (int*)(ws + 800320);
    int*   ssrc    = (int*)(ws + 801152);          // 3.2 MB -> ends 4,001,152

    // d_out layout: z [N*47] | y_pred [N*47] | S1 [N*256] | S2 [N*256]
    float* z     = (float*)d_out;
    float* ypred = z + (long long)N_NODES * D_OUT;
    float* S1    = ypred + (long long)N_NODES * D_OUT;
    float* S2    = S1 + (long long)N_NODES * D_HID;

    // --- CSR build (shared) ---
    detect_idx_kernel<<<1, 256, 0, stream>>>(ei, flag);
    hipMemsetAsync(degi, 0, N_NODES * sizeof(int), stream);
    count_deg_kernel<<<(N_EDGES + 255) / 256, 256, 0, stream>>>(ei, flag, degi);
    block_sum_kernel<<<SCAN_NBLK, 256, 0, stream>>>(degi, bsum);
    scan_bsums_kernel<<<1, 256, 0, stream>>>(bsum, row_ptr);
    fill_rowptr_kernel<<<SCAN_NBLK, 256, 0, stream>>>(degi, bsum, row_ptr, cursor, invd);
    fill_csr_kernel<<<(N_EDGES + 255) / 256, 256, 0, stream>>>(ei, flag, cursor, ssrc);

    const int gblocks = (N_NODES * 64 + 255) / 256;

    // FULL bf16-direct plan needs 94,059,904 B of ws
    if (ws_size >= 94059904ULL) {
        u16*   wt1l = (u16*)(ws + 4001152);
        u16*   wt1r = (u16*)(ws + 4066688);
        u16*   wt2l = (u16*)(ws + 4132224);
        u16*   wt2r = (u16*)(ws + 4263296);
        u16*   wt3  = (u16*)(ws + 4394368);
        u16*   xb   = (u16*)(ws + 4459904);        // N*128 bf16
        u16*   S1b  = (u16*)(ws + 17259904);       // N*256 bf16
        u16*   S2b  = (u16*)(ws + 42859904);       // N*256 bf16
        u16*   agg  = (u16*)(ws + 68459904);       // N*256 bf16 (reused as U fp32)
        float* U    = (float*)agg;

        convert_xb_kernel<<<(N_NODES * D_IN / 4 + 255) / 256, 256, 0, stream>>>(x, xb);
        build_wt_kernel<<<(229376 + 255) / 256, 256, 0, stream>>>(
            W1_l, W1_r, W2_l, W2_r, W3_l, W3_r, wt1l, wt1r, wt2l, wt2r, wt3);

        const dim3 gHid(2, (N_NODES + 127) / 128);   // M=256
        const dim3 gOut(1, (N_NODES + 127) / 128);   // M=94 (padded 128)

        // layer 1
        gather_mean_bf<128><<<gblocks, 256, 0, stream>>>(xb, row_ptr, ssrc, invd, agg);
        mfma_direct<<<gHid, 256, 0, stream>>>(agg, D_IN, wt1l, xb, D_IN, wt1r,
                                              b1, bn1_g, bn1_b, bn1_m, bn1_v,
                                              S1, D_HID, 1, 1, S1b, nullptr, 0);
        // layer 2
        gather_mean_bf<256><<<gblocks, 256, 0, stream>>>(S1b, row_ptr, ssrc, invd, agg);
        mfma_direct<<<gHid, 256, 0, stream>>>(agg, D_HID, wt2l, S1b, D_HID, wt2r,
                                              b2, bn2_g, bn2_b, bn2_m, bn2_v,
                                              S2, D_HID, 1, 1, S2b, nullptr, 0);
        // layer 3 (fused transform-first: U = S2@W3_l, z = S2@W3_r + b3)
        mfma_direct<<<gOut, 256, 0, stream>>>(S2b, D_HID, wt3, nullptr, 0, nullptr,
                                              b3, nullptr, nullptr, nullptr, nullptr,
                                              U, 94, 0, 0, nullptr, z, D_OUT);
        gather_add_out<<<gblocks, 256, 0, stream>>>(U, row_ptr, ssrc, invd, z);
    } else {
        // SAFE: R5 fp32-LDS pipeline (proven <= 55.2 MB)
        float* aggF = (float*)(ws + 4001152);      // N*256 fp32, ends 55,201,152
        float* U    = aggF;

        const dim3 gHid(D_HID / GBN, (N_NODES + GBM - 1) / GBM);
        const dim3 gOut(1, (N_NODES + GBM - 1) / GBM);

        gather_mean<128><<<gblocks, 256, 0, stream>>>(x, D_IN, row_ptr, ssrc, invd, aggF);
        mfma_gemm<<<gHid, 256, 0, stream>>>(aggF, W1_l, D_IN, x, W1_r, D_IN,
                                            b1, bn1_g, bn1_b, bn1_m, bn1_v,
                                            S1, D_HID, 1, 1);
        gather_mean<256><<<gblocks, 256, 0, stream>>>(S1, D_HID, row_ptr, ssrc, invd, aggF);
        mfma_gemm<<<gHid, 256, 0, stream>>>(aggF, W2_l, D_HID, S1, W2_r, D_HID,
                                            b2, bn2_g, bn2_b, bn2_m, bn2_v,
                                            S2, D_HID, 1, 1);
        mfma_gemm<<<gOut, 256, 0, stream>>>(S2, W3_l, D_HID, nullptr, nullptr, 0,
                                            nullptr, nullptr, nullptr, nullptr, nullptr,
                                            U, D_OUT, 0, 0);
        mfma_gemm<<<gOut, 256, 0, stream>>>(S2, W3_r, D_HID, nullptr, nullptr, 0,
                                            b3, nullptr, nullptr, nullptr, nullptr,
                                            z, D_OUT, 1, 0);
        gather_add_out<<<gblocks, 256, 0, stream>>>(U, row_ptr, ssrc, invd, z);
    }

    log_softmax_kernel<<<gblocks, 256, 0, stream>>>(z, ypred);
}